// Round 10
// baseline (152.846 us; speedup 1.0000x reference)
//
#include <hip/hip_runtime.h>
#include <math.h>

#define N_ANT 64
#define BATCH 131072
#define NSTEPS 63      // 31 internal softmax units + 32 leaf groups, DFS preorder
#define TPB 1024       // 16 waves; wave w owns m-tile w (weight cols 16w..16w+15)
#define NBLK 512       // 2 blocks/CU (48.5 KB LDS, 1024 thr -> both fit)
#define EPR 32         // elems per round
#define ROUNDS 8       // 256 elems per block
#define PSTR 130       // p-buffer ELEM-major row stride (floats): 63*2 + 4 pad

typedef float f32x4 __attribute__((ext_vector_type(4)));
typedef float v2f   __attribute__((ext_vector_type(2)));
typedef _Float16 f16x8 __attribute__((ext_vector_type(8)));
typedef _Float16 f16x4 __attribute__((ext_vector_type(4)));

static __device__ __forceinline__ float fast_rcp(float x) {
#if __has_builtin(__builtin_amdgcn_rcpf)
    return __builtin_amdgcn_rcpf(x);
#else
    return 1.0f / x;
#endif
}

// Advance DFS-preorder state over the complete binary tree.
// Internal units: l=0..4 (node n at layer l). Leaf groups: l==5 (group n).
static __device__ __forceinline__ void dfs_next(int& l, int& n) {
    if (l < 5) { l = l + 1; n = 2 * n; }
    else {
        while (n & 1) { n >>= 1; l--; }
        n += 1;
    }
}

__global__ __launch_bounds__(TPB) void beam_mfma(const float* __restrict__ x,
                                                 const float* __restrict__ t0,
                                                 const float* __restrict__ t1,
                                                 const float* __restrict__ t2,
                                                 const float* __restrict__ t3,
                                                 const float* __restrict__ t4,
                                                 float* __restrict__ out) {
    // x slice (32 elems x 128) as fp16, frag-swizzled, double-buffered (16 KB).
    __shared__ _Float16 xb[2][4096];
    // softmax pairs, ELEM-major [32 elems][PSTR], double-buffered (33.3 KB).
    __shared__ float pb[2][EPR * PSTR];

    const int tid = threadIdx.x;
    const int w   = tid >> 6;     // wave = m-tile (units 4w..4w+3)
    const int L   = tid & 63;
    const int q   = L >> 4;
    const int e15 = L & 15;

    // ---- W fragments (A-operand) computed IN-KERNEL for col m = 16w + e15.
    // A layout: element j of frag ks -> W[m][k = ks*32 + q*8 + j].
    // Real row m=2c -> [wr ; -wi] over k (a=k&63, hi=k>>6), m=2c+1 -> [wi; wr].
    // Two fp16 splits W = W1 + W2 (~2^-22); x kept single-split (R9-verified).
    f16x8 w1f[4], w2f[4];
#pragma unroll
    for (int ks = 0; ks < 4; ++ks) {
        w1f[ks] = (f16x8){0,0,0,0,0,0,0,0};
        w2f[ks] = (f16x8){0,0,0,0,0,0,0,0};
    }
    {
        const int m = 16 * w + e15;
        const int c = m >> 1, part = m & 1;
        const int su = c >> 1, kidx = c & 1;
        if (su < NSTEPS) {
            int l = 0, nn = 0;
            for (int i = 0; i < su; ++i) dfs_next(l, nn);
            const float* th = (l == 0) ? t0 : (l == 1) ? t1 : (l == 2) ? t2
                             : (l == 3) ? t3 : t4;
            const double step = (cos(M_PI - 1e-6) - 1.0) / 63.0;
            const double cosaz = 1.0 + (double)(2 * nn + kidx) * step;
#pragma unroll
            for (int aidx = 0; aidx < 16; ++aidx) {
                const int ks = aidx >> 3, j = aidx & 7;
                const int a = ks * 32 + q * 8 + j;   // antenna for frags ks, ks+2
                float wr, wi;
                if (l < 5) {
                    float theta = th[(nn * N_ANT + a) * 2 + kidx];
                    float sn, cs;
                    sincosf(theta, &sn, &cs);
                    wr = cs * 0.125f; wi = sn * 0.125f;
                } else {
                    // DFT leaf: phase = pi * a * cosaz; float sincospi of
                    // double-accurate argument (quantization ~1e-5 rad).
                    float tt = (float)((double)a * cosaz);
                    float sp, cp;
                    sincospif(tt, &sp, &cp);
                    wr = cp * 0.125f; wi = sp * 0.125f;
                }
                const float vlo = part ? wi : wr;           // hi=0 K-rows
                const float vhi = part ? wr : -wi;          // hi=1 K-rows
                _Float16 h;
                h = (_Float16)vlo;
                w1f[ks][j] = h; w2f[ks][j] = (_Float16)(vlo - (float)h);
                h = (_Float16)vhi;
                w1f[ks + 2][j] = h; w2f[ks + 2][j] = (_Float16)(vhi - (float)h);
            }
        }
    }

    // ---- Per-lane DFS metadata: lane u == DFS unit u in the tree phase.
    int myl = -1, myn = 0;
    {
        int cl = 0, cn = 0;
        for (int s = 0; s < NSTEPS; ++s) {
            if (s == L) { myl = cl; myn = cn; }
            dfs_next(cl, cn);
        }
    }
    // Leaf lane: DFS indices of its 5 internal ancestors + branch sides.
    const int sd0 = (myn >> 4) & 1, sd1 = (myn >> 3) & 1, sd2 = (myn >> 2) & 1,
              sd3 = (myn >> 1) & 1, sd4 = myn & 1;
    const int a0 = 0;
    const int a1 = a0 + 1 + sd0 * 31;   // subtree sizes 31,15,7,3
    const int a2 = a1 + 1 + sd1 * 15;
    const int a3 = a2 + 1 + sd2 * 7;
    const int a4 = a3 + 1 + sd3 * 3;

    // ---- Staging decode: thread handles 4 floats of the round's x slice.
    const int s_er = tid & 31;
    const int s_rt = tid >> 5;
    const int s_h  = s_rt & 1;
    const int s_q  = (s_rt >> 1) & 3;
    const int s_ks = s_rt >> 3;
    const int s_goff = s_er * 128 + s_ks * 32 + s_q * 8 + s_h * 4;       // floats
    const int s_loff = ((s_ks * 4 + s_q) * 32 + s_er) * 8 + s_h * 4;    // halves

    const long base = (long)blockIdx.x * (EPR * ROUNDS);

    // Prologue: stage slice 0.
    {
        float4 v = *(const float4*)(x + base * 128 + s_goff);
        f16x4 hv = {(_Float16)v.x, (_Float16)v.y, (_Float16)v.z, (_Float16)v.w};
        *(f16x4*)(&xb[0][s_loff]) = hv;
    }
    __syncthreads();

#pragma unroll 1
    for (int r = 0; r < ROUNDS; ++r) {
        const int cur = r & 1;
        const bool more = (r + 1 < ROUNDS);
        // Prefetch next slice early (HBM latency hidden under MFMA phase).
        float4 nv = {0.f, 0.f, 0.f, 0.f};
        if (more) nv = *(const float4*)(x + (base + (long)(r + 1) * EPR) * 128 + s_goff);

        // ---- MFMA: C[wcol][elem], 2 elem-groups, 2 W-split terms.
        f32x4 acc0 = {0,0,0,0}, acc1 = {0,0,0,0};
#pragma unroll
        for (int ks = 0; ks < 4; ++ks) {
            const _Float16* xc = &xb[cur][(size_t)((ks * 4 + q) * 32) * 8];
            f16x8 b0 = *(const f16x8*)(xc + e15 * 8);
            f16x8 b1 = *(const f16x8*)(xc + (16 + e15) * 8);
            acc0 = __builtin_amdgcn_mfma_f32_16x16x32_f16(w1f[ks], b0, acc0, 0, 0, 0);
            acc1 = __builtin_amdgcn_mfma_f32_16x16x32_f16(w1f[ks], b1, acc1, 0, 0, 0);
            acc0 = __builtin_amdgcn_mfma_f32_16x16x32_f16(w2f[ks], b0, acc0, 0, 0, 0);
            acc1 = __builtin_amdgcn_mfma_f32_16x16x32_f16(w2f[ks], b1, acc1, 0, 0, 0);
        }

        // ---- Stage next slice (cvt once per chunk, shared by all 16 waves).
        if (more) {
            f16x4 hv = {(_Float16)nv.x, (_Float16)nv.y, (_Float16)nv.z, (_Float16)nv.w};
            *(f16x4*)(&xb[cur ^ 1][s_loff]) = hv;
        }

        // ---- Lane-local softmax: lane holds (re0,im0,re1,im1) of unit u,
        // elem er = g*16+e15. Elem-major write: banks spread exactly evenly.
        const int u = 4 * w + q;
#pragma unroll
        for (int g = 0; g < 2; ++g) {
            f32x4 a = g ? acc1 : acc0;
            float g0 = fmaf(a.x, a.x, a.y * a.y);
            float g1 = fmaf(a.z, a.z, a.w * a.w);
            float m  = fmaxf(g0, g1);
            float e0 = __expf(g0 - m);
            float e1 = __expf(g1 - m);
            float inv = fast_rcp(e0 + e1);
            if (u < NSTEPS)   // u==63 = zero-padded cols, must not write
                *(v2f*)(&pb[cur][(g * 16 + e15) * PSTR + 2 * u]) =
                    (v2f){e0 * inv, e1 * inv};
        }
        __syncthreads();   // p(r) ready; xb[nxt] staged (barrier drains all)

        // ---- Tree: leaf lane reads own pair + 5 ancestors straight from LDS
        // (a0 broadcast, a1 2-addr, ... -> conflict-light), writes the elem's
        // output pair directly to global (32 leaf lanes cover the 256B row).
#pragma unroll
        for (int pass = 0; pass < 2; ++pass) {
            const int er = 2 * w + pass;   // wave handles elems 2w, 2w+1
            const float* prow = &pb[cur][er * PSTR];
            if (myl == 5) {
                v2f own = *(const v2f*)(prow + 2 * L);
                v2f q0 = *(const v2f*)(prow + 2 * a0);
                v2f q1 = *(const v2f*)(prow + 2 * a1);
                v2f q2 = *(const v2f*)(prow + 2 * a2);
                v2f q3 = *(const v2f*)(prow + 2 * a3);
                v2f q4 = *(const v2f*)(prow + 2 * a4);
                float P = (sd0 ? q0.y : q0.x) * (sd1 ? q1.y : q1.x)
                        * (sd2 ? q2.y : q2.x) * (sd3 ? q3.y : q3.x)
                        * (sd4 ? q4.y : q4.x);
                *(v2f*)(out + (base + (long)r * EPR + er) * 64 + 2 * myn) =
                    (v2f){P * own.x, P * own.y};
            }
        }
        // p(cur) reused only at round r+2, after everyone passed barrier(r+1).
    }
}

extern "C" void kernel_launch(void* const* d_in, const int* in_sizes, int n_in,
                              void* d_out, int out_size, void* d_ws, size_t ws_size,
                              hipStream_t stream) {
    const float* x  = (const float*)d_in[0];
    const float* t0 = (const float*)d_in[1];
    const float* t1 = (const float*)d_in[2];
    const float* t2 = (const float*)d_in[3];
    const float* t3 = (const float*)d_in[4];
    const float* t4 = (const float*)d_in[5];
    // Single kernel: W computed in-kernel (no fill pre-kernel, d_ws unused).
    beam_mfma<<<dim3(NBLK), dim3(TPB), 0, stream>>>(x, t0, t1, t2, t3, t4,
                                                    (float*)d_out);
}

// Round 11
// 147.125 us; speedup vs baseline: 1.0389x; 1.0389x over previous
//
#include <hip/hip_runtime.h>
#include <math.h>

#define N_ANT 64
#define BATCH 131072
#define NSTEPS 63      // 31 internal softmax units + 32 leaf groups, DFS preorder
#define TPB 1024       // 16 waves; wave w owns m-tile w (weight cols 16w..16w+15)
#define NBLK 512       // 2 blocks/CU co-resident (49.7 KB LDS each)
#define EPR 32         // elems per round
#define ROUNDS 8       // 256 elems per block
#define PSTR 130       // p-buffer ELEM-major row stride (floats): 63*2 + 4 pad

typedef float f32x4 __attribute__((ext_vector_type(4)));
typedef float v2f   __attribute__((ext_vector_type(2)));
typedef _Float16 f16x8 __attribute__((ext_vector_type(8)));
typedef _Float16 f16x4 __attribute__((ext_vector_type(4)));

static __device__ __forceinline__ float fast_rcp(float x) {
#if __has_builtin(__builtin_amdgcn_rcpf)
    return __builtin_amdgcn_rcpf(x);
#else
    return 1.0f / x;
#endif
}

// Advance DFS-preorder state over the complete binary tree.
// Internal units: l=0..4 (node n at layer l). Leaf groups: l==5 (group n).
static __device__ __forceinline__ void dfs_next(int& l, int& n) {
    if (l < 5) { l = l + 1; n = 2 * n; }
    else {
        while (n & 1) { n >>= 1; l--; }
        n += 1;
    }
}

// Build W operand (252 M x 128 K real, M 252..255 zero-padded) as TWO fp16
// splits (W = W1 + W2 to ~2^-22), prepacked in MFMA A-fragment order:
//   slot t = ((mtile*4 + kstep)*64 + lane), 8 contiguous fp16 per slot,
//   element j -> W[m = mtile*16 + (lane&15)][k = kstep*32 + (lane>>4)*8 + j].
// Real row m=2c -> [wr ; -wi] over k, m=2c+1 -> [wi ; wr]; unit s = c>>1 DFS.
__global__ void fill_B(const float* __restrict__ t0, const float* __restrict__ t1,
                       const float* __restrict__ t2, const float* __restrict__ t3,
                       const float* __restrict__ t4,
                       _Float16* __restrict__ B1p, _Float16* __restrict__ B2p) {
    const int t = blockIdx.x * 256 + threadIdx.x;   // 0..4095
    const int L = t & 63;
    const int kstep = (t >> 6) & 3;
    const int ntile = t >> 8;
    const int n = ntile * 16 + (L & 15);
    const int kbase = kstep * 32 + (L >> 4) * 8;

    f16x8 h1 = {0,0,0,0,0,0,0,0}, h2 = {0,0,0,0,0,0,0,0};
    if (n < 252) {
        const int c = n >> 1, part = n & 1;
        const int s = c >> 1, kidx = c & 1;
        int l = 0, nn = 0;
        for (int i = 0; i < s; ++i) dfs_next(l, nn);
#pragma unroll
        for (int j = 0; j < 8; ++j) {
            const int k = kbase + j;
            const int a = k & 63;       // antenna
            const int hi = k >> 6;      // 0: real-part rows, 1: imag-part rows
            float wr, wi;
            if (l < 5) {
                const float* th = (l == 0) ? t0 : (l == 1) ? t1 : (l == 2) ? t2
                                 : (l == 3) ? t3 : t4;
                float theta = th[(nn * N_ANT + a) * 2 + kidx];
                float sn, cs;
                sincosf(theta, &sn, &cs);
                wr = cs * 0.125f; wi = sn * 0.125f;
            } else {
                const int b = 2 * nn + kidx;
                const double step = (cos(M_PI - 1e-6) - 1.0) / 63.0;
                double cosaz = 1.0 + (double)b * step;
                double ph = M_PI * (double)a * cosaz;
                wr = (float)(cos(ph) * 0.125);
                wi = (float)(sin(ph) * 0.125);
            }
            float v = (part == 0) ? (hi == 0 ? wr : -wi)
                                  : (hi == 0 ? wi :  wr);
            _Float16 v1 = (_Float16)v;
            _Float16 v2 = (_Float16)(v - (float)v1);
            h1[j] = v1; h2[j] = v2;
        }
    }
    *(f16x8*)(B1p + (size_t)t * 8) = h1;
    *(f16x8*)(B2p + (size_t)t * 8) = h2;
}

__global__ __launch_bounds__(TPB) void beam_mfma(const float* __restrict__ x,
                                                 const _Float16* __restrict__ W1p,
                                                 const _Float16* __restrict__ W2p,
                                                 float* __restrict__ out) {
    // x slice (32 elems x 128) as fp16, frag-swizzled, double-buffered (16 KB).
    __shared__ _Float16 xb[2][4096];
    // softmax pairs, ELEM-major [32 elems][PSTR], double-buffered (33.3 KB).
    __shared__ float pb[2][EPR * PSTR];

    const int tid = threadIdx.x;
    const int w   = tid >> 6;     // wave = m-tile (units 4w..4w+3)
    const int L   = tid & 63;
    const int q   = L >> 4;
    const int e15 = L & 15;

    // ---- W fragments (A-operand) for m-tile w, both fp16 splits.
    f16x8 w1f[4], w2f[4];
#pragma unroll
    for (int ks = 0; ks < 4; ++ks) {
        w1f[ks] = *(const f16x8*)(W1p + (size_t)((w * 4 + ks) * 64 + L) * 8);
        w2f[ks] = *(const f16x8*)(W2p + (size_t)((w * 4 + ks) * 64 + L) * 8);
    }

    // ---- Per-lane DFS metadata: lane u == DFS unit u in the tree phase.
    int myl = -1, myn = 0;
    {
        int cl = 0, cn = 0;
        for (int s = 0; s < NSTEPS; ++s) {
            if (s == L) { myl = cl; myn = cn; }
            dfs_next(cl, cn);
        }
    }
    // Leaf lane: DFS indices of its 5 internal ancestors + branch sides.
    const int sd0 = (myn >> 4) & 1, sd1 = (myn >> 3) & 1, sd2 = (myn >> 2) & 1,
              sd3 = (myn >> 1) & 1, sd4 = myn & 1;
    const int a0 = 0;
    const int a1 = a0 + 1 + sd0 * 31;   // subtree sizes 31,15,7,3
    const int a2 = a1 + 1 + sd1 * 15;
    const int a3 = a2 + 1 + sd2 * 7;
    const int a4 = a3 + 1 + sd3 * 3;

    // ---- Staging decode: thread handles 4 floats of the round's x slice.
    const int s_er = tid & 31;
    const int s_rt = tid >> 5;
    const int s_h  = s_rt & 1;
    const int s_q  = (s_rt >> 1) & 3;
    const int s_ks = s_rt >> 3;
    const int s_goff = s_er * 128 + s_ks * 32 + s_q * 8 + s_h * 4;       // floats
    const int s_loff = ((s_ks * 4 + s_q) * 32 + s_er) * 8 + s_h * 4;    // halves

    const long base = (long)blockIdx.x * (EPR * ROUNDS);

    // Tree cascade for round rr using buffer bb (wave-private, elems 2w,2w+1).
    auto tree_pass = [&](int bb, int rr) {
#pragma unroll
        for (int pass = 0; pass < 2; ++pass) {
            const int er = 2 * w + pass;
            const float* prow = &pb[bb][er * PSTR];
            if (myl == 5) {
                v2f own = *(const v2f*)(prow + 2 * L);
                v2f q0 = *(const v2f*)(prow + 2 * a0);
                v2f q1 = *(const v2f*)(prow + 2 * a1);
                v2f q2 = *(const v2f*)(prow + 2 * a2);
                v2f q3 = *(const v2f*)(prow + 2 * a3);
                v2f q4 = *(const v2f*)(prow + 2 * a4);
                float P = (sd0 ? q0.y : q0.x) * (sd1 ? q1.y : q1.x)
                        * (sd2 ? q2.y : q2.x) * (sd3 ? q3.y : q3.x)
                        * (sd4 ? q4.y : q4.x);
                *(v2f*)(out + (base + (long)rr * EPR + er) * 64 + 2 * myn) =
                    (v2f){P * own.x, P * own.y};
            }
        }
    };

    // Prologue: stage slice 0.
    {
        float4 v = *(const float4*)(x + base * 128 + s_goff);
        f16x4 hv = {(_Float16)v.x, (_Float16)v.y, (_Float16)v.z, (_Float16)v.w};
        *(f16x4*)(&xb[0][s_loff]) = hv;
    }
    __syncthreads();

#pragma unroll 1
    for (int r = 0; r < ROUNDS; ++r) {
        const int cur = r & 1;
        const bool more = (r + 1 < ROUNDS);
        // Prefetch next slice (completes under the MFMA phase).
        float4 nv = {0.f, 0.f, 0.f, 0.f};
        if (more) nv = *(const float4*)(x + (base + (long)(r + 1) * EPR) * 128 + s_goff);

        // ---- MFMA: 4 independent chains (2 elem-groups x 2 W-split terms)
        // -> dependency depth 4 instead of 8.
        f32x4 acc0a = {0,0,0,0}, acc0b = {0,0,0,0};
        f32x4 acc1a = {0,0,0,0}, acc1b = {0,0,0,0};
#pragma unroll
        for (int ks = 0; ks < 4; ++ks) {
            const _Float16* xc = &xb[cur][(size_t)((ks * 4 + q) * 32) * 8];
            f16x8 b0 = *(const f16x8*)(xc + e15 * 8);
            f16x8 b1 = *(const f16x8*)(xc + (16 + e15) * 8);
            acc0a = __builtin_amdgcn_mfma_f32_16x16x32_f16(w1f[ks], b0, acc0a, 0, 0, 0);
            acc1a = __builtin_amdgcn_mfma_f32_16x16x32_f16(w1f[ks], b1, acc1a, 0, 0, 0);
            acc0b = __builtin_amdgcn_mfma_f32_16x16x32_f16(w2f[ks], b0, acc0b, 0, 0, 0);
            acc1b = __builtin_amdgcn_mfma_f32_16x16x32_f16(w2f[ks], b1, acc1b, 0, 0, 0);
        }

        // ---- Tree for the PREVIOUS round, hidden under the MFMA phase
        // (reads pb[cur^1]; softmax below writes pb[cur] — no overlap).
        if (r > 0) tree_pass(cur ^ 1, r - 1);

        // ---- Lane-local softmax: lane holds (re0,im0,re1,im1) of unit u,
        // elem er = g*16+e15. Elem-major write spreads banks evenly.
        const int u = 4 * w + q;
        f32x4 A0 = acc0a + acc0b;
        f32x4 A1 = acc1a + acc1b;
#pragma unroll
        for (int g = 0; g < 2; ++g) {
            f32x4 a = g ? A1 : A0;
            float g0 = fmaf(a.x, a.x, a.y * a.y);
            float g1 = fmaf(a.z, a.z, a.w * a.w);
            float m  = fmaxf(g0, g1);
            float e0 = __expf(g0 - m);
            float e1 = __expf(g1 - m);
            float inv = fast_rcp(e0 + e1);
            if (u < NSTEPS)   // u==63 = zero-padded cols, must not write
                *(v2f*)(&pb[cur][(g * 16 + e15) * PSTR + 2 * u]) =
                    (v2f){e0 * inv, e1 * inv};
        }

        // ---- Stage next slice (cvt once per chunk, shared by all 16 waves).
        if (more) {
            f16x4 hv = {(_Float16)nv.x, (_Float16)nv.y, (_Float16)nv.z, (_Float16)nv.w};
            *(f16x4*)(&xb[cur ^ 1][s_loff]) = hv;
        }
        __syncthreads();   // pb(cur) visible; xb(next) staged
    }

    // Epilogue: tree for the final round.
    tree_pass((ROUNDS - 1) & 1, ROUNDS - 1);
}

extern "C" void kernel_launch(void* const* d_in, const int* in_sizes, int n_in,
                              void* d_out, int out_size, void* d_ws, size_t ws_size,
                              hipStream_t stream) {
    const float* x  = (const float*)d_in[0];
    const float* t0 = (const float*)d_in[1];
    const float* t1 = (const float*)d_in[2];
    const float* t2 = (const float*)d_in[3];
    const float* t3 = (const float*)d_in[4];
    const float* t4 = (const float*)d_in[5];
    _Float16* W1p = (_Float16*)d_ws;                      // 64 KB
    _Float16* W2p = (_Float16*)((char*)d_ws + 65536);     // 64 KB

    fill_B<<<dim3(16), dim3(256), 0, stream>>>(t0, t1, t2, t3, t4, W1p, W2p);
    beam_mfma<<<dim3(NBLK), dim3(TPB), 0, stream>>>(x, W1p, W2p, (float*)d_out);
}

// Round 12
// 141.625 us; speedup vs baseline: 1.0792x; 1.0388x over previous
//
#include <hip/hip_runtime.h>
#include <math.h>

#define N_ANT 64
#define BATCH 131072
#define NSTEPS 63      // 31 internal softmax units + 32 leaf groups, DFS preorder
#define TPB 1024       // 16 waves; wave w owns m-tile w (weight cols 16w..16w+15)
#define NBLK 512       // 2 blocks/CU co-resident (49.7 KB LDS each)
#define EPR 32         // elems per round
#define ROUNDS 8       // 256 elems per block
#define PSTR 130       // p-buffer ELEM-major row stride (floats): 63*2 + 4 pad

typedef float f32x4 __attribute__((ext_vector_type(4)));
typedef float v2f   __attribute__((ext_vector_type(2)));
typedef _Float16 f16x8 __attribute__((ext_vector_type(8)));
typedef _Float16 f16x4 __attribute__((ext_vector_type(4)));

// Workgroup barrier WITHOUT the vmcnt(0) drain __syncthreads() forces.
// Cross-wave ordering here only ever communicates through LDS (xb staging,
// pb softmax pairs) -> draining lgkmcnt before s_barrier is sufficient.
// Output global stores are fire-and-forget; the x prefetch is a register
// dependency tracked by the compiler's own vmcnt bookkeeping.
#define BAR_LGKM() asm volatile("s_waitcnt lgkmcnt(0)\n\ts_barrier" ::: "memory")

static __device__ __forceinline__ float fast_rcp(float x) {
#if __has_builtin(__builtin_amdgcn_rcpf)
    return __builtin_amdgcn_rcpf(x);
#else
    return 1.0f / x;
#endif
}

// Advance DFS-preorder state over the complete binary tree.
// Internal units: l=0..4 (node n at layer l). Leaf groups: l==5 (group n).
static __device__ __forceinline__ void dfs_next(int& l, int& n) {
    if (l < 5) { l = l + 1; n = 2 * n; }
    else {
        while (n & 1) { n >>= 1; l--; }
        n += 1;
    }
}

// Build W operand (252 M x 128 K real, M 252..255 zero-padded) as TWO fp16
// splits (W = W1 + W2 to ~2^-22), prepacked in MFMA A-fragment order:
//   slot t = ((mtile*4 + kstep)*64 + lane), 8 contiguous fp16 per slot,
//   element j -> W[m = mtile*16 + (lane&15)][k = kstep*32 + (lane>>4)*8 + j].
// Real row m=2c -> [wr ; -wi] over k, m=2c+1 -> [wi ; wr]; unit s = c>>1 DFS.
__global__ void fill_B(const float* __restrict__ t0, const float* __restrict__ t1,
                       const float* __restrict__ t2, const float* __restrict__ t3,
                       const float* __restrict__ t4,
                       _Float16* __restrict__ B1p, _Float16* __restrict__ B2p) {
    const int t = blockIdx.x * 256 + threadIdx.x;   // 0..4095
    const int L = t & 63;
    const int kstep = (t >> 6) & 3;
    const int ntile = t >> 8;
    const int n = ntile * 16 + (L & 15);
    const int kbase = kstep * 32 + (L >> 4) * 8;

    f16x8 h1 = {0,0,0,0,0,0,0,0}, h2 = {0,0,0,0,0,0,0,0};
    if (n < 252) {
        const int c = n >> 1, part = n & 1;
        const int s = c >> 1, kidx = c & 1;
        int l = 0, nn = 0;
        for (int i = 0; i < s; ++i) dfs_next(l, nn);
#pragma unroll
        for (int j = 0; j < 8; ++j) {
            const int k = kbase + j;
            const int a = k & 63;       // antenna
            const int hi = k >> 6;      // 0: real-part rows, 1: imag-part rows
            float wr, wi;
            if (l < 5) {
                const float* th = (l == 0) ? t0 : (l == 1) ? t1 : (l == 2) ? t2
                                 : (l == 3) ? t3 : t4;
                float theta = th[(nn * N_ANT + a) * 2 + kidx];
                float sn, cs;
                sincosf(theta, &sn, &cs);
                wr = cs * 0.125f; wi = sn * 0.125f;
            } else {
                const int b = 2 * nn + kidx;
                const double step = (cos(M_PI - 1e-6) - 1.0) / 63.0;
                double cosaz = 1.0 + (double)b * step;
                double ph = M_PI * (double)a * cosaz;
                wr = (float)(cos(ph) * 0.125);
                wi = (float)(sin(ph) * 0.125);
            }
            float v = (part == 0) ? (hi == 0 ? wr : -wi)
                                  : (hi == 0 ? wi :  wr);
            _Float16 v1 = (_Float16)v;
            _Float16 v2 = (_Float16)(v - (float)v1);
            h1[j] = v1; h2[j] = v2;
        }
    }
    *(f16x8*)(B1p + (size_t)t * 8) = h1;
    *(f16x8*)(B2p + (size_t)t * 8) = h2;
}

__global__ __launch_bounds__(TPB) void beam_mfma(const float* __restrict__ x,
                                                 const _Float16* __restrict__ W1p,
                                                 const _Float16* __restrict__ W2p,
                                                 float* __restrict__ out) {
    // x slice (32 elems x 128) as fp16, frag-swizzled, double-buffered (16 KB).
    __shared__ _Float16 xb[2][4096];
    // softmax pairs, ELEM-major [32 elems][PSTR], double-buffered (33.3 KB).
    __shared__ float pb[2][EPR * PSTR];

    const int tid = threadIdx.x;
    const int w   = tid >> 6;     // wave = m-tile (units 4w..4w+3)
    const int L   = tid & 63;
    const int q   = L >> 4;
    const int e15 = L & 15;

    // ---- W fragments (A-operand) for m-tile w, both fp16 splits.
    f16x8 w1f[4], w2f[4];
#pragma unroll
    for (int ks = 0; ks < 4; ++ks) {
        w1f[ks] = *(const f16x8*)(W1p + (size_t)((w * 4 + ks) * 64 + L) * 8);
        w2f[ks] = *(const f16x8*)(W2p + (size_t)((w * 4 + ks) * 64 + L) * 8);
    }

    // ---- Per-lane DFS metadata: lane u == DFS unit u in the tree phase.
    int myl = -1, myn = 0;
    {
        int cl = 0, cn = 0;
        for (int s = 0; s < NSTEPS; ++s) {
            if (s == L) { myl = cl; myn = cn; }
            dfs_next(cl, cn);
        }
    }
    // Leaf lane: DFS indices of its 5 internal ancestors + branch sides.
    const int sd0 = (myn >> 4) & 1, sd1 = (myn >> 3) & 1, sd2 = (myn >> 2) & 1,
              sd3 = (myn >> 1) & 1, sd4 = myn & 1;
    const int a0 = 0;
    const int a1 = a0 + 1 + sd0 * 31;   // subtree sizes 31,15,7,3
    const int a2 = a1 + 1 + sd1 * 15;
    const int a3 = a2 + 1 + sd2 * 7;
    const int a4 = a3 + 1 + sd3 * 3;

    // ---- Staging decode: thread handles 4 floats of the round's x slice.
    const int s_er = tid & 31;
    const int s_rt = tid >> 5;
    const int s_h  = s_rt & 1;
    const int s_q  = (s_rt >> 1) & 3;
    const int s_ks = s_rt >> 3;
    const int s_goff = s_er * 128 + s_ks * 32 + s_q * 8 + s_h * 4;       // floats
    const int s_loff = ((s_ks * 4 + s_q) * 32 + s_er) * 8 + s_h * 4;    // halves

    const long base = (long)blockIdx.x * (EPR * ROUNDS);

    // Tree cascade for round rr using buffer bb (wave-private, elems 2w,2w+1).
    auto tree_pass = [&](int bb, int rr) {
#pragma unroll
        for (int pass = 0; pass < 2; ++pass) {
            const int er = 2 * w + pass;
            const float* prow = &pb[bb][er * PSTR];
            if (myl == 5) {
                v2f own = *(const v2f*)(prow + 2 * L);
                v2f q0 = *(const v2f*)(prow + 2 * a0);
                v2f q1 = *(const v2f*)(prow + 2 * a1);
                v2f q2 = *(const v2f*)(prow + 2 * a2);
                v2f q3 = *(const v2f*)(prow + 2 * a3);
                v2f q4 = *(const v2f*)(prow + 2 * a4);
                float P = (sd0 ? q0.y : q0.x) * (sd1 ? q1.y : q1.x)
                        * (sd2 ? q2.y : q2.x) * (sd3 ? q3.y : q3.x)
                        * (sd4 ? q4.y : q4.x);
                *(v2f*)(out + (base + (long)rr * EPR + er) * 64 + 2 * myn) =
                    (v2f){P * own.x, P * own.y};
            }
        }
    };

    // Prologue: stage slice 0; pre-load slice 1 into registers.
    {
        float4 v = *(const float4*)(x + base * 128 + s_goff);
        f16x4 hv = {(_Float16)v.x, (_Float16)v.y, (_Float16)v.z, (_Float16)v.w};
        *(f16x4*)(&xb[0][s_loff]) = hv;
    }
    float4 nv = {0.f, 0.f, 0.f, 0.f};
    if (ROUNDS > 1) nv = *(const float4*)(x + (base + EPR) * 128 + s_goff);
    BAR_LGKM();

#pragma unroll 1
    for (int r = 0; r < ROUNDS; ++r) {
        const int cur = r & 1;
        // Issue the r+2 load now: a full round between issue and use.
        float4 nv2 = {0.f, 0.f, 0.f, 0.f};
        if (r + 2 < ROUNDS)
            nv2 = *(const float4*)(x + (base + (long)(r + 2) * EPR) * 128 + s_goff);

        // ---- MFMA: 4 independent chains (2 elem-groups x 2 W-split terms).
        f32x4 acc0a = {0,0,0,0}, acc0b = {0,0,0,0};
        f32x4 acc1a = {0,0,0,0}, acc1b = {0,0,0,0};
#pragma unroll
        for (int ks = 0; ks < 4; ++ks) {
            const _Float16* xc = &xb[cur][(size_t)((ks * 4 + q) * 32) * 8];
            f16x8 b0 = *(const f16x8*)(xc + e15 * 8);
            f16x8 b1 = *(const f16x8*)(xc + (16 + e15) * 8);
            acc0a = __builtin_amdgcn_mfma_f32_16x16x32_f16(w1f[ks], b0, acc0a, 0, 0, 0);
            acc1a = __builtin_amdgcn_mfma_f32_16x16x32_f16(w1f[ks], b1, acc1a, 0, 0, 0);
            acc0b = __builtin_amdgcn_mfma_f32_16x16x32_f16(w2f[ks], b0, acc0b, 0, 0, 0);
            acc1b = __builtin_amdgcn_mfma_f32_16x16x32_f16(w2f[ks], b1, acc1b, 0, 0, 0);
        }

        // ---- Tree for the PREVIOUS round, hidden under the MFMA phase
        // (reads pb[cur^1]; softmax below writes pb[cur] — disjoint).
        if (r > 0) tree_pass(cur ^ 1, r - 1);

        // ---- Lane-local softmax: lane holds (re0,im0,re1,im1) of unit u,
        // elem er = g*16+e15. Elem-major write spreads banks evenly.
        const int u = 4 * w + q;
        f32x4 A0 = acc0a + acc0b;
        f32x4 A1 = acc1a + acc1b;
#pragma unroll
        for (int g = 0; g < 2; ++g) {
            f32x4 a = g ? A1 : A0;
            float g0 = fmaf(a.x, a.x, a.y * a.y);
            float g1 = fmaf(a.z, a.z, a.w * a.w);
            float m  = fmaxf(g0, g1);
            float e0 = __expf(g0 - m);
            float e1 = __expf(g1 - m);
            float inv = fast_rcp(e0 + e1);
            if (u < NSTEPS)   // u==63 = zero-padded cols, must not write
                *(v2f*)(&pb[cur][(g * 16 + e15) * PSTR + 2 * u]) =
                    (v2f){e0 * inv, e1 * inv};
        }

        // ---- Stage slice r+1 (loaded a full round ago -> latency hidden).
        if (r + 1 < ROUNDS) {
            f16x4 hv = {(_Float16)nv.x, (_Float16)nv.y, (_Float16)nv.z, (_Float16)nv.w};
            *(f16x4*)(&xb[cur ^ 1][s_loff]) = hv;
        }
        nv = nv2;

        BAR_LGKM();   // LDS visibility only; no vmcnt drain of stores/prefetch
    }

    // Epilogue: tree for the final round.
    tree_pass((ROUNDS - 1) & 1, ROUNDS - 1);
}

extern "C" void kernel_launch(void* const* d_in, const int* in_sizes, int n_in,
                              void* d_out, int out_size, void* d_ws, size_t ws_size,
                              hipStream_t stream) {
    const float* x  = (const float*)d_in[0];
    const float* t0 = (const float*)d_in[1];
    const float* t1 = (const float*)d_in[2];
    const float* t2 = (const float*)d_in[3];
    const float* t3 = (const float*)d_in[4];
    const float* t4 = (const float*)d_in[5];
    _Float16* W1p = (_Float16*)d_ws;                      // 64 KB
    _Float16* W2p = (_Float16*)((char*)d_ws + 65536);     // 64 KB

    fill_B<<<dim3(16), dim3(256), 0, stream>>>(t0, t1, t2, t3, t4, W1p, W2p);
    beam_mfma<<<dim3(NBLK), dim3(TPB), 0, stream>>>(x, W1p, W2p, (float*)d_out);
}